// Round 6
// baseline (813.192 us; speedup 1.0000x reference)
//
#include <hip/hip_runtime.h>
#include <math.h>

typedef float    f32x4 __attribute__((ext_vector_type(4)));
typedef unsigned u32x4 __attribute__((ext_vector_type(4)));
typedef short    s16x8 __attribute__((ext_vector_type(8)));

#define N_TOT 16384
#define C_TOT 1000
#define D_TOT 512
#define NC ((size_t)N_TOT * C_TOT)

#define EPS_F 1e-8f
#define SCALE_F 0.04419417382415922f  // 1/sqrt(512)

#define BN 128
#define BC 64
#define BD 16            // f32 k-depth per stage (row = 64 B)
#define NT (D_TOT / BD)  // 32

#define GL_LDS(gp, lp)                                                        \
    __builtin_amdgcn_global_load_lds(                                         \
        (const __attribute__((address_space(1))) void*)(gp),                  \
        (__attribute__((address_space(3))) void*)(lp), 16, 0, 0)

// ---------------- fsq / csq precompute: one wave per row ----------------
__global__ __launch_bounds__(256)
void sq_kernel(const float* __restrict__ F, const float* __restrict__ Cc,
               float* __restrict__ sqout) {
    int gw   = (blockIdx.x * 256 + threadIdx.x) >> 6;
    int lane = threadIdx.x & 63;
    if (gw >= N_TOT + C_TOT) return;
    const float* src = (gw < N_TOT) ? (F + (size_t)gw * D_TOT)
                                    : (Cc + (size_t)(gw - N_TOT) * D_TOT);
    f32x4 a = *(const f32x4*)(src + lane * 4);
    f32x4 b = *(const f32x4*)(src + 256 + lane * 4);
    float acc = a[0] * a[0];
    acc = fmaf(a[1], a[1], acc);
    acc = fmaf(a[2], a[2], acc);
    acc = fmaf(a[3], a[3], acc);
    acc = fmaf(b[0], b[0], acc);
    acc = fmaf(b[1], b[1], acc);
    acc = fmaf(b[2], b[2], acc);
    acc = fmaf(b[3], b[3], acc);
    #pragma unroll
    for (int off = 32; off > 0; off >>= 1)
        acc += __shfl_xor(acc, off);
    if (lane == 0) sqout[gw] = acc;
}

__device__ inline unsigned cvtpk_bf16(float lo, float hi) {
    unsigned r;
    asm("v_cvt_pk_bf16_f32 %0, %1, %2" : "=v"(r) : "v"(lo), "v"(hi));
    return r;
}

// ---------------- fused L1 (f32 VALU) + dot (bf16 MFMA) ----------------
// LDS: f32 rows of 16 (64 B). Rows 0..127 = F, 128..191 = C.
// Source-side swizzle (both F and C): 16B slot s of row r holds global slot
// s ^ ((r>>2)&3).  global_load_lds dest is wave-uniform base + lane*16 (m104).
// MFMA: one mfma_f32_16x16x32_bf16 per tile-PAIR; lane group g = lane>>4 needs
// k = 8g..8g+7 of the pair -> parity myp = g>>1 selects even/odd tile, slot
// pair sb = 2*(g&1). Frags cvt'd f32->bf16 in-register (v_cvt_pk_bf16_f32).
__global__ __launch_bounds__(256)
void dist_fused(const float* __restrict__ F, const float* __restrict__ Cc,
                const float* __restrict__ sqbuf, float* __restrict__ out) {
    __shared__ float lds[2][192 * BD];

    const int tid  = threadIdx.x;
    const int lane = tid & 63;
    const int wid  = tid >> 6;
    const int tx   = tid & 15;   // valu: centroid cols tx + 16j
    const int ty   = tid >> 4;   // valu: feature rows ty + 16i
    const int wr   = wid >> 1;   // mfma: feature 64-half
    const int wc   = wid & 1;    // mfma: centroid 32-half
    const int c0   = blockIdx.x * BC;
    const int n0   = blockIdx.y * BN;

    // staging: srow = tid>>2 (0..63), slot = tid&3; swizzled on global source
    const int srow = tid >> 2;
    const int s0   = tid & 3;
    const int ssw  = s0 ^ ((srow >> 2) & 3);  // same for srow and srow+64
    const float* gF0 = F + (size_t)(n0 + srow) * D_TOT + ssw * 4;
    const float* gF1 = gF0 + (size_t)64 * D_TOT;
    const float* gC  = Cc + (size_t)(c0 + srow) * D_TOT + ssw * 4;
    const bool   cok = (c0 + srow) < C_TOT;
    const int    w16 = wid * 16;  // wave-uniform dest row base

    // mfma frag geometry
    const int g   = lane >> 4;
    const int myp = g >> 1;        // tile parity this half-wave loads
    const int sb  = (g & 1) * 2;   // f32 slot pair within the 16-float row

    f32x4 l1v[8];
    #pragma unroll
    for (int i = 0; i < 8; ++i) l1v[i] = (f32x4)(0.f);
    f32x4 acc[4][2];
    #pragma unroll
    for (int fi = 0; fi < 4; ++fi)
        #pragma unroll
        for (int fj = 0; fj < 2; ++fj) acc[fi][fj] = (f32x4)(0.f);
    s16x8 afr[4], bfr[2];

    // prologue: stage tile 0 into buffer 0
    GL_LDS(gF0, &lds[0][w16 * BD]);
    GL_LDS(gF1, &lds[0][(64 + w16) * BD]);
    if (cok) GL_LDS(gC, &lds[0][(128 + w16) * BD]);
    __syncthreads();

    const int crs = (tx >> 2) & 3;  // C reader swizzle (j-invariant)
    const int frs = (ty >> 2) & 3;  // F reader swizzle (i-invariant)

    for (int t = 0; t < NT; ++t) {
        if (t + 1 < NT) {
            const int nb = (t + 1) & 1;
            const int d1 = (t + 1) * BD;
            GL_LDS(gF0 + d1, &lds[nb][w16 * BD]);
            GL_LDS(gF1 + d1, &lds[nb][(64 + w16) * BD]);
            if (cok) GL_LDS(gC + d1, &lds[nb][(128 + w16) * BD]);
        }
        const float* lf = lds[t & 1];

        // ---- MFMA fragment assembly (half-wave per parity) ----
        if ((t & 1) == myp) {
            #pragma unroll
            for (int fi = 0; fi < 4; ++fi) {
                int R  = wr * 64 + fi * 16 + (lane & 15);
                int sz = (R >> 2) & 3;
                f32x4 lo = *(const f32x4*)&lf[R * 16 + ((sb ^ sz) << 2)];
                f32x4 hi = *(const f32x4*)&lf[R * 16 + (((sb + 1) ^ sz) << 2)];
                u32x4 w;
                w[0] = cvtpk_bf16(lo[0], lo[1]); w[1] = cvtpk_bf16(lo[2], lo[3]);
                w[2] = cvtpk_bf16(hi[0], hi[1]); w[3] = cvtpk_bf16(hi[2], hi[3]);
                afr[fi] = __builtin_bit_cast(s16x8, w);
            }
            #pragma unroll
            for (int fj = 0; fj < 2; ++fj) {
                int R  = wc * 32 + fj * 16 + (lane & 15);
                int sz = (R >> 2) & 3;
                f32x4 lo = *(const f32x4*)&lf[(128 + R) * 16 + ((sb ^ sz) << 2)];
                f32x4 hi = *(const f32x4*)&lf[(128 + R) * 16 + (((sb + 1) ^ sz) << 2)];
                u32x4 w;
                w[0] = cvtpk_bf16(lo[0], lo[1]); w[1] = cvtpk_bf16(lo[2], lo[3]);
                w[2] = cvtpk_bf16(hi[0], hi[1]); w[3] = cvtpk_bf16(hi[2], hi[3]);
                bfr[fj] = __builtin_bit_cast(s16x8, w);
            }
        }
        if (t & 1) {  // full frags (even+odd tile halves) ready
            #pragma unroll
            for (int fi = 0; fi < 4; ++fi)
                #pragma unroll
                for (int fj = 0; fj < 2; ++fj)
                    acc[fi][fj] = __builtin_amdgcn_mfma_f32_16x16x32_bf16(
                        afr[fi], bfr[fj], acc[fi][fj], 0, 0, 0);
        }

        // ---- VALU L1: 2 ops/elem (sub + abs-folded add) ----
        #pragma unroll
        for (int q = 0; q < 4; ++q) {
            const int cq = (q ^ crs) << 2;
            const int fq = (q ^ frs) << 2;
            f32x4 cv0 = *(const f32x4*)&lf[(128 + tx) * 16 + cq];
            f32x4 cv1 = *(const f32x4*)&lf[(128 + tx + 16) * 16 + cq];
            f32x4 cv2 = *(const f32x4*)&lf[(128 + tx + 32) * 16 + cq];
            f32x4 cv3 = *(const f32x4*)&lf[(128 + tx + 48) * 16 + cq];
            #pragma unroll
            for (int i = 0; i < 8; ++i) {
                f32x4 fv = *(const f32x4*)&lf[(ty + 16 * i) * 16 + fq];
                #pragma unroll
                for (int k = 0; k < 4; ++k) {
                    l1v[i][0] += fabsf(fv[k] - cv0[k]);
                    l1v[i][1] += fabsf(fv[k] - cv1[k]);
                    l1v[i][2] += fabsf(fv[k] - cv2[k]);
                    l1v[i][3] += fabsf(fv[k] - cv3[k]);
                }
            }
        }
        __syncthreads();
    }

    // ---------------- epilogue ----------------
    // L1 (valu mapping)
    #pragma unroll
    for (int i = 0; i < 8; ++i) {
        const size_t rb = (size_t)(n0 + ty + 16 * i) * C_TOT;
        #pragma unroll
        for (int j = 0; j < 4; ++j) {
            const int c = c0 + tx + 16 * j;
            if (c < C_TOT) out[rb + c] = l1v[i][j] * SCALE_F;
        }
    }

    // L2 + cos (mfma D mapping: col = lane&15, row = 4*(lane>>4)+reg; R4-validated)
    const float* csq = sqbuf + N_TOT;
    #pragma unroll
    for (int fj = 0; fj < 2; ++fj) {
        const int c = c0 + wc * 32 + fj * 16 + (lane & 15);
        if (c < C_TOT) {
            const float cs = csq[c];
            const float cn = fmaxf(sqrtf(cs), EPS_F);
            #pragma unroll
            for (int fi = 0; fi < 4; ++fi) {
                const int mbase = n0 + wr * 64 + fi * 16 + ((lane >> 4) << 2);
                #pragma unroll
                for (int reg = 0; reg < 4; ++reg) {
                    const float fsv = sqbuf[mbase + reg];
                    const float fnv = fmaxf(sqrtf(fsv), EPS_F);
                    const float dv  = acc[fi][fj][reg];
                    const size_t p  = (size_t)(mbase + reg) * C_TOT + c;
                    const float sqv = fmaxf(fsv + cs - 2.0f * dv, 0.f);
                    out[NC + p]     = sqrtf(sqv) * SCALE_F;
                    out[2 * NC + p] = dv * SCALE_F / (fnv * cn);
                }
            }
        }
    }
}

extern "C" void kernel_launch(void* const* d_in, const int* in_sizes, int n_in,
                              void* d_out, int out_size, void* d_ws, size_t ws_size,
                              hipStream_t stream) {
    const float* F  = (const float*)d_in[0];
    const float* Cc = (const float*)d_in[1];
    float* out   = (float*)d_out;
    float* sqbuf = (float*)d_ws;   // [N_TOT + C_TOT] f32

    int rows = N_TOT + C_TOT;
    sq_kernel<<<(rows + 3) / 4, 256, 0, stream>>>(F, Cc, sqbuf);
    dist_fused<<<dim3(1024 / BC, N_TOT / BN), 256, 0, stream>>>(F, Cc, sqbuf, out);
}

// Round 7
// 582.817 us; speedup vs baseline: 1.3953x; 1.3953x over previous
//
#include <hip/hip_runtime.h>
#include <math.h>

typedef float f32x4 __attribute__((ext_vector_type(4)));
typedef short s16x8 __attribute__((ext_vector_type(8)));

#define N_TOT 16384
#define C_TOT 1000
#define C_PAD 1024
#define D_TOT 512
#define NC ((size_t)N_TOT * C_TOT)

#define EPS_F 1e-8f
#define SCALE_F 0.04419417382415922f  // 1/sqrt(512)

#define GL_LDS(gp, lp)                                                        \
    __builtin_amdgcn_global_load_lds(                                         \
        (const __attribute__((address_space(1))) void*)(gp),                  \
        (__attribute__((address_space(3))) void*)(lp), 16, 0, 0)

// ---------------- fsq / csq precompute: one wave per row ----------------
__global__ __launch_bounds__(256)
void sq_kernel(const float* __restrict__ F, const float* __restrict__ Cc,
               float* __restrict__ sqout) {
    int gw   = (blockIdx.x * 256 + threadIdx.x) >> 6;
    int lane = threadIdx.x & 63;
    if (gw >= N_TOT + C_TOT) return;
    const float* src = (gw < N_TOT) ? (F + (size_t)gw * D_TOT)
                                    : (Cc + (size_t)(gw - N_TOT) * D_TOT);
    f32x4 a = *(const f32x4*)(src + lane * 4);
    f32x4 b = *(const f32x4*)(src + 256 + lane * 4);
    float acc = a[0] * a[0];
    acc = fmaf(a[1], a[1], acc);
    acc = fmaf(a[2], a[2], acc);
    acc = fmaf(a[3], a[3], acc);
    acc = fmaf(b[0], b[0], acc);
    acc = fmaf(b[1], b[1], acc);
    acc = fmaf(b[2], b[2], acc);
    acc = fmaf(b[3], b[3], acc);
    #pragma unroll
    for (int off = 32; off > 0; off >>= 1)
        acc += __shfl_xor(acc, off);
    if (lane == 0) sqout[gw] = acc;
}

// ---------------- f32 -> bf16 (RNE) convert, C zero-padded to 1024 rows ----
__device__ inline short f2bf(float x) {
    union { float f; unsigned u; } v; v.f = x;
    unsigned r = (v.u + 0x7FFFu + ((v.u >> 16) & 1u)) >> 16;
    return (short)r;
}

__global__ __launch_bounds__(256)
void cvt_kernel(const float* __restrict__ F, const float* __restrict__ Cc,
                short* __restrict__ Fbf, short* __restrict__ Cbf) {
    const int FS8 = N_TOT * D_TOT / 8;   // 1048576
    const int CS8 = C_PAD * D_TOT / 8;   // 65536
    int gid = blockIdx.x * 256 + threadIdx.x;
    if (gid < FS8) {
        const float* s = F + (size_t)gid * 8;
        f32x4 a = *(const f32x4*)s;
        f32x4 b = *(const f32x4*)(s + 4);
        s16x8 o;
        o[0] = f2bf(a[0]); o[1] = f2bf(a[1]); o[2] = f2bf(a[2]); o[3] = f2bf(a[3]);
        o[4] = f2bf(b[0]); o[5] = f2bf(b[1]); o[6] = f2bf(b[2]); o[7] = f2bf(b[3]);
        *(s16x8*)(Fbf + (size_t)gid * 8) = o;
    } else if (gid < FS8 + CS8) {
        int j = gid - FS8;
        int base = j * 8;
        int crow = base >> 9;
        s16x8 o = (s16x8)(short)0;
        if (crow < C_TOT) {
            const float* s = Cc + (size_t)base;
            f32x4 a = *(const f32x4*)s;
            f32x4 b = *(const f32x4*)(s + 4);
            o[0] = f2bf(a[0]); o[1] = f2bf(a[1]); o[2] = f2bf(a[2]); o[3] = f2bf(a[3]);
            o[4] = f2bf(b[0]); o[5] = f2bf(b[1]); o[6] = f2bf(b[2]); o[7] = f2bf(b[3]);
        }
        *(s16x8*)(Cbf + (size_t)base) = o;
    }
}

// ---------------- bf16 MFMA dot GEMM -> writes L2 and cos (R4-validated) ---
__global__ __launch_bounds__(256)
void dot_gemm(const short* __restrict__ Fbf, const short* __restrict__ Cbf,
              const float* __restrict__ sqbuf, float* __restrict__ out) {
    __shared__ short lds[2][8192];   // A: [0,4096), B: [4096,8192)

    const int tid  = threadIdx.x;
    const int lane = tid & 63;
    const int wid  = tid >> 6;
    const int wr   = wid >> 1;
    const int wc   = wid & 1;
    const int m0   = blockIdx.y * 128;
    const int n0   = blockIdx.x * 128;

    const int row0 = tid >> 2;
    const int row1 = row0 + 64;
    const int slot = tid & 3;
    const int sw0  = slot ^ ((row0 >> 1) & 3);
    const int sw1  = slot ^ ((row1 >> 1) & 3);
    const short* sA0 = Fbf + (size_t)(m0 + row0) * D_TOT + sw0 * 8;
    const short* sA1 = Fbf + (size_t)(m0 + row1) * D_TOT + sw1 * 8;
    const short* sB0 = Cbf + (size_t)(n0 + row0) * D_TOT + sw0 * 8;
    const short* sB1 = Cbf + (size_t)(n0 + row1) * D_TOT + sw1 * 8;

    int offA[4], offB[4];
    #pragma unroll
    for (int fi = 0; fi < 4; ++fi) {
        int R = wr * 64 + fi * 16 + (lane & 15);
        offA[fi] = R * 32 + (((lane >> 4) ^ ((R >> 1) & 3)) << 3);
    }
    #pragma unroll
    for (int fj = 0; fj < 4; ++fj) {
        int R = wc * 64 + fj * 16 + (lane & 15);
        offB[fj] = 4096 + R * 32 + (((lane >> 4) ^ ((R >> 1) & 3)) << 3);
    }

    f32x4 acc[4][4];
    #pragma unroll
    for (int fi = 0; fi < 4; ++fi)
        #pragma unroll
        for (int fj = 0; fj < 4; ++fj) acc[fi][fj] = (f32x4)(0.f);

    GL_LDS(sA0, &lds[0][(size_t)tid * 8]);
    GL_LDS(sA1, &lds[0][(size_t)(tid + 256) * 8]);
    GL_LDS(sB0, &lds[0][4096 + (size_t)tid * 8]);
    GL_LDS(sB1, &lds[0][4096 + (size_t)(tid + 256) * 8]);
    __syncthreads();

    const int NK = D_TOT / 32;   // 16
    for (int kt = 0; kt < NK; ++kt) {
        if (kt + 1 < NK) {
            const int nb = (kt + 1) & 1;
            const int d1 = (kt + 1) * 32;
            GL_LDS(sA0 + d1, &lds[nb][(size_t)tid * 8]);
            GL_LDS(sA1 + d1, &lds[nb][(size_t)(tid + 256) * 8]);
            GL_LDS(sB0 + d1, &lds[nb][4096 + (size_t)tid * 8]);
            GL_LDS(sB1 + d1, &lds[nb][4096 + (size_t)(tid + 256) * 8]);
        }
        const short* lb = lds[kt & 1];
        s16x8 af[4], bg[4];
        #pragma unroll
        for (int fi = 0; fi < 4; ++fi) af[fi] = *(const s16x8*)&lb[offA[fi]];
        #pragma unroll
        for (int fj = 0; fj < 4; ++fj) bg[fj] = *(const s16x8*)&lb[offB[fj]];
        #pragma unroll
        for (int fi = 0; fi < 4; ++fi)
            #pragma unroll
            for (int fj = 0; fj < 4; ++fj)
                acc[fi][fj] = __builtin_amdgcn_mfma_f32_16x16x32_bf16(
                    af[fi], bg[fj], acc[fi][fj], 0, 0, 0);
        __syncthreads();
    }

    // epilogue: D layout col = lane&15, row = 4*(lane>>4) + reg  [m89/m91]
    const float* csq = sqbuf + N_TOT;
    float fs_[4][4], fn_[4][4];
    #pragma unroll
    for (int fi = 0; fi < 4; ++fi)
        #pragma unroll
        for (int reg = 0; reg < 4; ++reg) {
            int m = m0 + wr * 64 + fi * 16 + ((lane >> 4) << 2) + reg;
            float v = sqbuf[m];
            fs_[fi][reg] = v;
            fn_[fi][reg] = fmaxf(sqrtf(v), EPS_F);
        }
    #pragma unroll
    for (int fj = 0; fj < 4; ++fj) {
        int c = n0 + wc * 64 + fj * 16 + (lane & 15);
        if (c < C_TOT) {
            float cs = csq[c];
            float cn = fmaxf(sqrtf(cs), EPS_F);
            #pragma unroll
            for (int fi = 0; fi < 4; ++fi) {
                int mrow = m0 + wr * 64 + fi * 16 + ((lane >> 4) << 2);
                #pragma unroll
                for (int reg = 0; reg < 4; ++reg) {
                    float d = acc[fi][fj][reg];
                    size_t p = (size_t)(mrow + reg) * C_TOT + c;
                    float sqv = fmaxf(fs_[fi][reg] + cs - 2.0f * d, 0.f);
                    out[NC + p]     = sqrtf(sqv) * SCALE_F;
                    out[2 * NC + p] = (d * SCALE_F) / (fn_[fi][reg] * cn);
                }
            }
        }
    }
}

// ---------------- L1-only kernel: exact R3 structure minus sq-fma ----------
// LDS rows of 16 f32 (64 B): rows 0..127 = F, 128..191 = C. C source-swizzled
// (slot s of row r holds k-slot s ^ ((r>>2)&3)); measured 0 bank conflicts.
__global__ __launch_bounds__(256)
void l1_main(const float* __restrict__ F, const float* __restrict__ Cc,
             float* __restrict__ out) {
    __shared__ float lds[2][192 * 16];

    const int tid = threadIdx.x;
    const int tx  = tid & 15;    // centroid dir: cols tx + 16*j
    const int ty  = tid >> 4;    // feature dir:  rows ty + 16*i
    const int c0  = blockIdx.x * 64;
    const int n0  = blockIdx.y * 128;

    const int srow  = tid >> 2;        // 0..63
    const int sslot = tid & 3;
    const int w16   = (tid >> 6) * 16;

    const float* fA = F + (size_t)(n0 + srow) * D_TOT + sslot * 4;
    const float* fB = fA + (size_t)64 * D_TOT;
    const int cswz  = sslot ^ ((srow >> 2) & 3);
    const float* cP = Cc + (size_t)(c0 + srow) * D_TOT + cswz * 4;
    const bool cok  = (c0 + srow) < C_TOT;

    f32x4 l1v[8];
    #pragma unroll
    for (int i = 0; i < 8; ++i) l1v[i] = (f32x4)(0.f);

    GL_LDS(fA, &lds[0][w16 * 16]);
    GL_LDS(fB, &lds[0][(64 + w16) * 16]);
    if (cok) GL_LDS(cP, &lds[0][(128 + w16) * 16]);
    __syncthreads();

    const int NT  = 32;
    const int crs = (tx >> 2) & 3;

    for (int t = 0; t < NT; ++t) {
        if (t + 1 < NT) {
            const int nb = (t + 1) & 1;
            const int d1 = (t + 1) * 16;
            GL_LDS(fA + d1, &lds[nb][w16 * 16]);
            GL_LDS(fB + d1, &lds[nb][(64 + w16) * 16]);
            if (cok) GL_LDS(cP + d1, &lds[nb][(128 + w16) * 16]);
        }

        const float* lf = &lds[t & 1][0];
        #pragma unroll
        for (int q = 0; q < 4; ++q) {
            const int cq = (q ^ crs) << 2;
            f32x4 cv0 = *(const f32x4*)&lf[(128 + tx) * 16 + cq];
            f32x4 cv1 = *(const f32x4*)&lf[(128 + tx + 16) * 16 + cq];
            f32x4 cv2 = *(const f32x4*)&lf[(128 + tx + 32) * 16 + cq];
            f32x4 cv3 = *(const f32x4*)&lf[(128 + tx + 48) * 16 + cq];
            #pragma unroll
            for (int i = 0; i < 8; ++i) {
                f32x4 fv = *(const f32x4*)&lf[((ty + 16 * i) << 4) + (q << 2)];
                #pragma unroll
                for (int k = 0; k < 4; ++k) {
                    l1v[i][0] += fabsf(fv[k] - cv0[k]);
                    l1v[i][1] += fabsf(fv[k] - cv1[k]);
                    l1v[i][2] += fabsf(fv[k] - cv2[k]);
                    l1v[i][3] += fabsf(fv[k] - cv3[k]);
                }
            }
        }
        __syncthreads();
    }

    #pragma unroll
    for (int i = 0; i < 8; ++i) {
        const size_t rb = (size_t)(n0 + ty + 16 * i) * C_TOT;
        #pragma unroll
        for (int j = 0; j < 4; ++j) {
            const int c = c0 + tx + 16 * j;
            if (c < C_TOT) out[rb + c] = l1v[i][j] * SCALE_F;
        }
    }
}

extern "C" void kernel_launch(void* const* d_in, const int* in_sizes, int n_in,
                              void* d_out, int out_size, void* d_ws, size_t ws_size,
                              hipStream_t stream) {
    const float* F  = (const float*)d_in[0];
    const float* Cc = (const float*)d_in[1];
    float* out   = (float*)d_out;
    float* sqbuf = (float*)d_ws;                 // [N_TOT + C_TOT] f32

    // bf16 scratch parked in the (not-yet-written) L1 region of out:
    // 17.8 MB < NC*4 B = 65.5 MB; dot_gemm reads it and writes only L2/cos
    // regions; l1_main overwrites the L1 region afterwards. (R4-validated.)
    short* Fbf = (short*)out;
    short* Cbf = Fbf + (size_t)N_TOT * D_TOT;

    int rows = N_TOT + C_TOT;
    sq_kernel<<<(rows + 3) / 4, 256, 0, stream>>>(F, Cc, sqbuf);
    cvt_kernel<<<(N_TOT * D_TOT / 8 + C_PAD * D_TOT / 8 + 255) / 256, 256, 0,
                 stream>>>(F, Cc, Fbf, Cbf);
    dot_gemm<<<dim3(8, 128), 256, 0, stream>>>(Fbf, Cbf, sqbuf, out);
    l1_main<<<dim3(16, 128), 256, 0, stream>>>(F, Cc, out);
}

// Round 8
// 376.976 us; speedup vs baseline: 2.1571x; 1.5460x over previous
//
#include <hip/hip_runtime.h>
#include <math.h>

typedef float f32x4 __attribute__((ext_vector_type(4)));
typedef short s16x8 __attribute__((ext_vector_type(8)));

#define N_TOT 16384
#define C_TOT 1000
#define C_PAD 1024
#define D_TOT 512
#define NC ((size_t)N_TOT * C_TOT)

#define EPS_F 1e-8f
#define SCALE_F 0.04419417382415922f  // 1/sqrt(512)

#define GL_LDS(gp, lp)                                                        \
    __builtin_amdgcn_global_load_lds(                                         \
        (const __attribute__((address_space(1))) void*)(gp),                  \
        (__attribute__((address_space(3))) void*)(lp), 16, 0, 0)

// ---------------- fsq / csq precompute: one wave per row ----------------
__global__ __launch_bounds__(256)
void sq_kernel(const float* __restrict__ F, const float* __restrict__ Cc,
               float* __restrict__ sqout) {
    int gw   = (blockIdx.x * 256 + threadIdx.x) >> 6;
    int lane = threadIdx.x & 63;
    if (gw >= N_TOT + C_TOT) return;
    const float* src = (gw < N_TOT) ? (F + (size_t)gw * D_TOT)
                                    : (Cc + (size_t)(gw - N_TOT) * D_TOT);
    f32x4 a = *(const f32x4*)(src + lane * 4);
    f32x4 b = *(const f32x4*)(src + 256 + lane * 4);
    float acc = a[0] * a[0];
    acc = fmaf(a[1], a[1], acc);
    acc = fmaf(a[2], a[2], acc);
    acc = fmaf(a[3], a[3], acc);
    acc = fmaf(b[0], b[0], acc);
    acc = fmaf(b[1], b[1], acc);
    acc = fmaf(b[2], b[2], acc);
    acc = fmaf(b[3], b[3], acc);
    #pragma unroll
    for (int off = 32; off > 0; off >>= 1)
        acc += __shfl_xor(acc, off);
    if (lane == 0) sqout[gw] = acc;
}

// ---------------- f32 -> bf16 (RNE) convert, C zero-padded to 1024 rows ----
__device__ inline short f2bf(float x) {
    union { float f; unsigned u; } v; v.f = x;
    unsigned r = (v.u + 0x7FFFu + ((v.u >> 16) & 1u)) >> 16;
    return (short)r;
}

__global__ __launch_bounds__(256)
void cvt_kernel(const float* __restrict__ F, const float* __restrict__ Cc,
                short* __restrict__ Fbf, short* __restrict__ Cbf) {
    const int FS8 = N_TOT * D_TOT / 8;   // 1048576
    const int CS8 = C_PAD * D_TOT / 8;   // 65536
    int gid = blockIdx.x * 256 + threadIdx.x;
    if (gid < FS8) {
        const float* s = F + (size_t)gid * 8;
        f32x4 a = *(const f32x4*)s;
        f32x4 b = *(const f32x4*)(s + 4);
        s16x8 o;
        o[0] = f2bf(a[0]); o[1] = f2bf(a[1]); o[2] = f2bf(a[2]); o[3] = f2bf(a[3]);
        o[4] = f2bf(b[0]); o[5] = f2bf(b[1]); o[6] = f2bf(b[2]); o[7] = f2bf(b[3]);
        *(s16x8*)(Fbf + (size_t)gid * 8) = o;
    } else if (gid < FS8 + CS8) {
        int j = gid - FS8;
        int base = j * 8;
        int crow = base >> 9;
        s16x8 o = (s16x8)(short)0;
        if (crow < C_TOT) {
            const float* s = Cc + (size_t)base;
            f32x4 a = *(const f32x4*)s;
            f32x4 b = *(const f32x4*)(s + 4);
            o[0] = f2bf(a[0]); o[1] = f2bf(a[1]); o[2] = f2bf(a[2]); o[3] = f2bf(a[3]);
            o[4] = f2bf(b[0]); o[5] = f2bf(b[1]); o[6] = f2bf(b[2]); o[7] = f2bf(b[3]);
        }
        *(s16x8*)(Cbf + (size_t)base) = o;
    }
}

// ---------------- bf16 MFMA dot GEMM -> writes L2 and cos (R4-validated) ---
__global__ __launch_bounds__(256)
void dot_gemm(const short* __restrict__ Fbf, const short* __restrict__ Cbf,
              const float* __restrict__ sqbuf, float* __restrict__ out) {
    __shared__ short lds[2][8192];   // A: [0,4096), B: [4096,8192)

    const int tid  = threadIdx.x;
    const int lane = tid & 63;
    const int wid  = tid >> 6;
    const int wr   = wid >> 1;
    const int wc   = wid & 1;
    const int m0   = blockIdx.y * 128;
    const int n0   = blockIdx.x * 128;

    const int row0 = tid >> 2;
    const int row1 = row0 + 64;
    const int slot = tid & 3;
    const int sw0  = slot ^ ((row0 >> 1) & 3);
    const int sw1  = slot ^ ((row1 >> 1) & 3);
    const short* sA0 = Fbf + (size_t)(m0 + row0) * D_TOT + sw0 * 8;
    const short* sA1 = Fbf + (size_t)(m0 + row1) * D_TOT + sw1 * 8;
    const short* sB0 = Cbf + (size_t)(n0 + row0) * D_TOT + sw0 * 8;
    const short* sB1 = Cbf + (size_t)(n0 + row1) * D_TOT + sw1 * 8;

    int offA[4], offB[4];
    #pragma unroll
    for (int fi = 0; fi < 4; ++fi) {
        int R = wr * 64 + fi * 16 + (lane & 15);
        offA[fi] = R * 32 + (((lane >> 4) ^ ((R >> 1) & 3)) << 3);
    }
    #pragma unroll
    for (int fj = 0; fj < 4; ++fj) {
        int R = wc * 64 + fj * 16 + (lane & 15);
        offB[fj] = 4096 + R * 32 + (((lane >> 4) ^ ((R >> 1) & 3)) << 3);
    }

    f32x4 acc[4][4];
    #pragma unroll
    for (int fi = 0; fi < 4; ++fi)
        #pragma unroll
        for (int fj = 0; fj < 4; ++fj) acc[fi][fj] = (f32x4)(0.f);

    GL_LDS(sA0, &lds[0][(size_t)tid * 8]);
    GL_LDS(sA1, &lds[0][(size_t)(tid + 256) * 8]);
    GL_LDS(sB0, &lds[0][4096 + (size_t)tid * 8]);
    GL_LDS(sB1, &lds[0][4096 + (size_t)(tid + 256) * 8]);
    __syncthreads();

    const int NK = D_TOT / 32;   // 16
    for (int kt = 0; kt < NK; ++kt) {
        if (kt + 1 < NK) {
            const int nb = (kt + 1) & 1;
            const int d1 = (kt + 1) * 32;
            GL_LDS(sA0 + d1, &lds[nb][(size_t)tid * 8]);
            GL_LDS(sA1 + d1, &lds[nb][(size_t)(tid + 256) * 8]);
            GL_LDS(sB0 + d1, &lds[nb][4096 + (size_t)tid * 8]);
            GL_LDS(sB1 + d1, &lds[nb][4096 + (size_t)(tid + 256) * 8]);
        }
        const short* lb = lds[kt & 1];
        s16x8 af[4], bg[4];
        #pragma unroll
        for (int fi = 0; fi < 4; ++fi) af[fi] = *(const s16x8*)&lb[offA[fi]];
        #pragma unroll
        for (int fj = 0; fj < 4; ++fj) bg[fj] = *(const s16x8*)&lb[offB[fj]];
        #pragma unroll
        for (int fi = 0; fi < 4; ++fi)
            #pragma unroll
            for (int fj = 0; fj < 4; ++fj)
                acc[fi][fj] = __builtin_amdgcn_mfma_f32_16x16x32_bf16(
                    af[fi], bg[fj], acc[fi][fj], 0, 0, 0);
        __syncthreads();
    }

    // epilogue: D layout col = lane&15, row = 4*(lane>>4) + reg  [m89/m91]
    const float* csq = sqbuf + N_TOT;
    float fs_[4][4], fn_[4][4];
    #pragma unroll
    for (int fi = 0; fi < 4; ++fi)
        #pragma unroll
        for (int reg = 0; reg < 4; ++reg) {
            int m = m0 + wr * 64 + fi * 16 + ((lane >> 4) << 2) + reg;
            float v = sqbuf[m];
            fs_[fi][reg] = v;
            fn_[fi][reg] = fmaxf(sqrtf(v), EPS_F);
        }
    #pragma unroll
    for (int fj = 0; fj < 4; ++fj) {
        int c = n0 + wc * 64 + fj * 16 + (lane & 15);
        if (c < C_TOT) {
            float cs = csq[c];
            float cn = fmaxf(sqrtf(cs), EPS_F);
            #pragma unroll
            for (int fi = 0; fi < 4; ++fi) {
                int mrow = m0 + wr * 64 + fi * 16 + ((lane >> 4) << 2);
                #pragma unroll
                for (int reg = 0; reg < 4; ++reg) {
                    float d = acc[fi][fj][reg];
                    size_t p = (size_t)(mrow + reg) * C_TOT + c;
                    float sqv = fmaxf(fs_[fi][reg] + cs - 2.0f * d, 0.f);
                    out[NC + p]     = sqrtf(sqv) * SCALE_F;
                    out[2 * NC + p] = (d * SCALE_F) / (fn_[fi][reg] * cn);
                }
            }
        }
    }
}

// ---------------- L1-only kernel: R7 structure, asm abs-folded accumulate --
// LDS rows of 16 f32 (64 B): rows 0..127 = F, 128..191 = C. C source-swizzled
// (slot s of row r holds k-slot s ^ ((r>>2)&3)); measured 0 bank conflicts.
// Accumulate via v_add_f32 with VOP3 abs() input modifier: 2 VALU insts/elem.
__device__ inline void add_abs(float& acc, float d) {
    asm("v_add_f32 %0, %0, abs(%1)" : "+v"(acc) : "v"(d));
}

__global__ __launch_bounds__(256)
void l1_main(const float* __restrict__ F, const float* __restrict__ Cc,
             float* __restrict__ out) {
    __shared__ float lds[2][192 * 16];

    const int tid = threadIdx.x;
    const int tx  = tid & 15;    // centroid dir: cols tx + 16*j
    const int ty  = tid >> 4;    // feature dir:  rows ty + 16*i
    const int c0  = blockIdx.x * 64;
    const int n0  = blockIdx.y * 128;

    const int srow  = tid >> 2;        // 0..63
    const int sslot = tid & 3;
    const int w16   = (tid >> 6) * 16;

    const float* fA = F + (size_t)(n0 + srow) * D_TOT + sslot * 4;
    const float* fB = fA + (size_t)64 * D_TOT;
    const int cswz  = sslot ^ ((srow >> 2) & 3);
    const float* cP = Cc + (size_t)(c0 + srow) * D_TOT + cswz * 4;
    const bool cok  = (c0 + srow) < C_TOT;

    f32x4 l1v[8];
    #pragma unroll
    for (int i = 0; i < 8; ++i) l1v[i] = (f32x4)(0.f);

    GL_LDS(fA, &lds[0][w16 * 16]);
    GL_LDS(fB, &lds[0][(64 + w16) * 16]);
    if (cok) GL_LDS(cP, &lds[0][(128 + w16) * 16]);
    __syncthreads();

    const int NT  = 32;
    const int crs = (tx >> 2) & 3;

    for (int t = 0; t < NT; ++t) {
        if (t + 1 < NT) {
            const int nb = (t + 1) & 1;
            const int d1 = (t + 1) * 16;
            GL_LDS(fA + d1, &lds[nb][w16 * 16]);
            GL_LDS(fB + d1, &lds[nb][(64 + w16) * 16]);
            if (cok) GL_LDS(cP + d1, &lds[nb][(128 + w16) * 16]);
        }

        const float* lf = &lds[t & 1][0];
        #pragma unroll
        for (int q = 0; q < 4; ++q) {
            const int cq = (q ^ crs) << 2;
            f32x4 cv0 = *(const f32x4*)&lf[(128 + tx) * 16 + cq];
            f32x4 cv1 = *(const f32x4*)&lf[(128 + tx + 16) * 16 + cq];
            f32x4 cv2 = *(const f32x4*)&lf[(128 + tx + 32) * 16 + cq];
            f32x4 cv3 = *(const f32x4*)&lf[(128 + tx + 48) * 16 + cq];
            #pragma unroll
            for (int i = 0; i < 8; ++i) {
                f32x4 fv = *(const f32x4*)&lf[((ty + 16 * i) << 4) + (q << 2)];
                float a0 = l1v[i][0], a1 = l1v[i][1];
                float a2 = l1v[i][2], a3 = l1v[i][3];
                #pragma unroll
                for (int k = 0; k < 4; ++k) {
                    add_abs(a0, fv[k] - cv0[k]);
                    add_abs(a1, fv[k] - cv1[k]);
                    add_abs(a2, fv[k] - cv2[k]);
                    add_abs(a3, fv[k] - cv3[k]);
                }
                l1v[i][0] = a0; l1v[i][1] = a1;
                l1v[i][2] = a2; l1v[i][3] = a3;
            }
        }
        __syncthreads();
    }

    #pragma unroll
    for (int i = 0; i < 8; ++i) {
        const size_t rb = (size_t)(n0 + ty + 16 * i) * C_TOT;
        #pragma unroll
        for (int j = 0; j < 4; ++j) {
            const int c = c0 + tx + 16 * j;
            if (c < C_TOT) out[rb + c] = l1v[i][j] * SCALE_F;
        }
    }
}

extern "C" void kernel_launch(void* const* d_in, const int* in_sizes, int n_in,
                              void* d_out, int out_size, void* d_ws, size_t ws_size,
                              hipStream_t stream) {
    const float* F  = (const float*)d_in[0];
    const float* Cc = (const float*)d_in[1];
    float* out   = (float*)d_out;
    float* sqbuf = (float*)d_ws;                 // [N_TOT + C_TOT] f32

    // bf16 scratch parked in the (not-yet-written) L1 region of out:
    // 17.8 MB < NC*4 B = 65.5 MB; dot_gemm reads it and writes only L2/cos
    // regions; l1_main overwrites the L1 region afterwards. (R4-validated.)
    short* Fbf = (short*)out;
    short* Cbf = Fbf + (size_t)N_TOT * D_TOT;

    int rows = N_TOT + C_TOT;
    sq_kernel<<<(rows + 3) / 4, 256, 0, stream>>>(F, Cc, sqbuf);
    cvt_kernel<<<(N_TOT * D_TOT / 8 + C_PAD * D_TOT / 8 + 255) / 256, 256, 0,
                 stream>>>(F, Cc, Fbf, Cbf);
    dot_gemm<<<dim3(8, 128), 256, 0, stream>>>(Fbf, Cbf, sqbuf, out);
    l1_main<<<dim3(16, 128), 256, 0, stream>>>(F, Cc, out);
}